// Round 4
// baseline (898.666 us; speedup 1.0000x reference)
//
#include <hip/hip_runtime.h>
#include <hip/hip_bf16.h>
#include <math.h>

typedef __hip_bfloat16 bf16;

static constexpr int cB  = 2;
static constexpr int cC  = 128;
static constexpr int cH  = 128;
static constexpr int cW  = 128;
static constexpr int cP  = cH * cW;       // 16384
static constexpr int cC3 = 384;
static constexpr int cHID = 340;
static constexpr int cNW = 1024;          // (128/4)^2 windows
static constexpr float cEPS = 1e-6f;

__device__ __forceinline__ float bfu2f(unsigned short u){
  union { unsigned int i; float f; } c; c.i = ((unsigned int)u) << 16; return c.f;
}
__device__ __forceinline__ float b2f(bf16 v){ return __bfloat162float(v); }

// ---------------- zero small buffer ----------------
__global__ void k_zero(float* __restrict__ p, int n){
  int i = blockIdx.x * 256 + threadIdx.x;
  if (i < n) p[i] = 0.f;
}

// ---------------- channel LayerNorm per pixel (optionally a+r), dst roll shift ----
// a, r: fp32 trunk buffers; out: bf16 (feeds GEMMs)
template<int HAS_ADD>
__global__ void __launch_bounds__(256) k_ln(const float* __restrict__ a,
                                            const float* __restrict__ r,
                                            const float* __restrict__ gamma,
                                            const float* __restrict__ beta,
                                            bf16* __restrict__ out, int sh, int sw){
  int idx = blockIdx.x * 256 + threadIdx.x;
  if (idx >= cB * cP) return;
  int b = idx >> 14;
  int p = idx & (cP - 1);
  const float* ap = a + (size_t)b * cC * cP + p;
  const float* rp = r + (size_t)b * cC * cP + p;
  float s = 0.f, ss = 0.f;
  #pragma unroll 8
  for (int c = 0; c < cC; c++){
    float v = ap[c * cP];
    if (HAS_ADD) v += rp[c * cP];
    s += v; ss += v * v;
  }
  float m = s * (1.f / cC);
  float var = ss * (1.f / cC) - m * m;
  float rstd = rsqrtf(var + cEPS);
  int h = p >> 7, w = p & 127;
  int h2 = (h + sh) & (cH - 1);
  int w2 = (w + sw) & (cW - 1);
  bf16* op = out + (size_t)b * cC * cP + h2 * cW + w2;
  #pragma unroll 8
  for (int c = 0; c < cC; c++){
    float v = ap[c * cP];
    if (HAS_ADD) v += rp[c * cP];
    op[c * cP] = __float2bfloat16((v - m) * rstd * gamma[c] + beta[c]);
  }
}

// ---------------- conv1x1 as GEMM: out[b,m,p] = sum_k W[m,k]*X[b,k,p] (+R) ------
// 64x64 tile, BK=16, 256 threads, 4x4 micro-tile, fp32 accumulate.
// W fp32, X bf16.  MODE: 0 = bf16 out, 1 = f32 out, 2 = f32 out + f32 residual.
template<int MODE>
__global__ void __launch_bounds__(256) k_gemm(const float* __restrict__ Wm,
                                              const bf16* __restrict__ X,
                                              const float* __restrict__ R,
                                              void* __restrict__ Out,
                                              int M, int K){
  __shared__ float Ws[16][64];
  __shared__ float Xs[16][64];
  int b  = blockIdx.z;
  int m0 = blockIdx.y * 64;
  int p0 = blockIdx.x * 64;
  int t  = threadIdx.x;
  int ty = t >> 4, tx = t & 15;
  const bf16* Xb = X + (size_t)b * K * cP;
  float acc[4][4] = {};
  int wm = t >> 2;            // 0..63  (W row within tile)
  int wk = (t & 3) * 4;       // 0,4,8,12
  int xk = t >> 4;            // 0..15
  int xn = (t & 15) * 4;
  for (int k0 = 0; k0 < K; k0 += 16){
    if (m0 + 64 <= M && k0 + 16 <= K){
      float4 wv = *(const float4*)(Wm + (size_t)(m0 + wm) * K + k0 + wk);
      Ws[wk + 0][wm] = wv.x;
      Ws[wk + 1][wm] = wv.y;
      Ws[wk + 2][wm] = wv.z;
      Ws[wk + 3][wm] = wv.w;
    } else {
      #pragma unroll
      for (int i = 0; i < 4; i++){
        int mm = m0 + wm, kk = k0 + wk + i;
        Ws[wk + i][wm] = (mm < M && kk < K) ? Wm[(size_t)mm * K + kk] : 0.f;
      }
    }
    if (k0 + xk < K){
      ushort4 xv = *(const ushort4*)(Xb + (size_t)(k0 + xk) * cP + p0 + xn);
      Xs[xk][xn + 0] = bfu2f(xv.x);
      Xs[xk][xn + 1] = bfu2f(xv.y);
      Xs[xk][xn + 2] = bfu2f(xv.z);
      Xs[xk][xn + 3] = bfu2f(xv.w);
    } else {
      Xs[xk][xn + 0] = 0.f; Xs[xk][xn + 1] = 0.f;
      Xs[xk][xn + 2] = 0.f; Xs[xk][xn + 3] = 0.f;
    }
    __syncthreads();
    #pragma unroll
    for (int kk = 0; kk < 16; kk++){
      float4 a4 = *(const float4*)&Ws[kk][ty * 4];
      float4 b4 = *(const float4*)&Xs[kk][tx * 4];
      float av[4] = {a4.x, a4.y, a4.z, a4.w};
      float bv[4] = {b4.x, b4.y, b4.z, b4.w};
      #pragma unroll
      for (int i = 0; i < 4; i++)
        #pragma unroll
        for (int j = 0; j < 4; j++)
          acc[i][j] += av[i] * bv[j];
    }
    __syncthreads();
  }
  #pragma unroll
  for (int i = 0; i < 4; i++){
    int m = m0 + ty * 4 + i;
    if (m >= M) continue;
    size_t base = (size_t)b * M * cP + (size_t)m * cP + p0 + tx * 4;
    if (MODE == 0){
      bf16 tv[4];
      #pragma unroll
      for (int j = 0; j < 4; j++) tv[j] = __float2bfloat16(acc[i][j]);
      *(ushort4*)((unsigned short*)Out + base) = *(const ushort4*)tv;
    } else {
      float4 ov;
      if (MODE == 2){
        float4 rv = *(const float4*)(R + base);
        ov = make_float4(acc[i][0] + rv.x, acc[i][1] + rv.y,
                         acc[i][2] + rv.z, acc[i][3] + rv.w);
      } else {
        ov = make_float4(acc[i][0], acc[i][1], acc[i][2], acc[i][3]);
      }
      *(float4*)((float*)Out + base) = ov;
    }
  }
}

// ---------------- depthwise 3x3 SAME (zero pad), optional exact gelu ------------
template<int GELU>
__global__ void __launch_bounds__(256) k_dw(const bf16* __restrict__ in,
                                            const float* __restrict__ wt,
                                            bf16* __restrict__ out, int CCn){
  int idx = blockIdx.x * 256 + threadIdx.x;
  if (idx >= cB * CCn * cP) return;
  int p  = idx & (cP - 1);
  int bc = idx >> 14;
  int c  = bc % CCn;
  int h = p >> 7, w = p & 127;
  const bf16* ip = in + (size_t)bc * cP;
  float acc = 0.f;
  #pragma unroll
  for (int ky = 0; ky < 3; ky++){
    int hh = h + ky - 1;
    if ((unsigned)hh >= (unsigned)cH) continue;
    #pragma unroll
    for (int kx = 0; kx < 3; kx++){
      int ww = w + kx - 1;
      if ((unsigned)ww >= (unsigned)cW) continue;
      acc += wt[c * 9 + ky * 3 + kx] * b2f(ip[hh * cW + ww]);
    }
  }
  if (GELU) acc = 0.5f * acc * (1.f + erff(acc * 0.70710678118654752f));
  out[idx] = __float2bfloat16(acc);
}

// ---------------- RSA window attention: one block per (b, 4x4 window) -----------
// qkv: [b,384,P] bf16 (already rolled frame). out written with +2,+2 roll-back shift.
__global__ void __launch_bounds__(256) k_rsa(const bf16* __restrict__ qkv,
                                             const float* __restrict__ temp,
                                             bf16* __restrict__ out){
  __shared__ float qs[16][128];
  __shared__ float ks[16][128];
  __shared__ float vs[16][128];
  __shared__ float at[64][132];
  __shared__ float invq[16], invk[16];
  int blk = blockIdx.x;
  int b  = blk >> 10;
  int nw = blk & 1023;
  int hb = nw >> 5, wb = nw & 31;
  int t = threadIdx.x;
  const bf16* base = qkv + (size_t)b * cC3 * cP;
  for (int idx = t; idx < 2048; idx += 256){
    int p = idx & 15, c = idx >> 4;
    int off = (hb * 4 + (p >> 2)) * cW + wb * 4 + (p & 3);
    qs[p][c] = b2f(base[(size_t)c * cP + off]);
    ks[p][c] = b2f(base[(size_t)(c + 128) * cP + off]);
    vs[p][c] = b2f(base[(size_t)(c + 256) * cP + off]);
  }
  __syncthreads();
  if (t < 32){
    int rr = t & 15;
    const float* row = (t < 16) ? qs[rr] : ks[rr];
    float s = 0.f;
    #pragma unroll
    for (int i = 0; i < 128; i += 4){
      float4 v = *(const float4*)(row + i);
      s += v.x*v.x + v.y*v.y + v.z*v.z + v.w*v.w;
    }
    float inv = 1.f / fmaxf(sqrtf(s), 1e-12f);
    if (t < 16) invq[rr] = inv; else invk[rr] = inv;
  }
  __syncthreads();
  for (int idx = t; idx < 2048; idx += 256){
    int p = idx & 15, c = idx >> 4;
    qs[p][c] *= invq[p] * invk[p];     // fold both l2-norms into q
  }
  float T = temp[0];
  int c0 = (t >> 4) * 4;     // attn-phase row group (within 64-row half)
  int d0 = (t & 15) * 8;     // attn-phase / out-phase col group
  int pp = t >> 4;           // out-phase window pixel
  float o[8] = {0,0,0,0,0,0,0,0};
  for (int half = 0; half < 2; half++){
    __syncthreads();
    float acc[4][8] = {};
    for (int p = 0; p < 16; p++){
      float4 qa = *(const float4*)&qs[p][half * 64 + c0];
      float4 ka = *(const float4*)&ks[p][d0];
      float4 kb = *(const float4*)&ks[p][d0 + 4];
      float qv[4] = {qa.x, qa.y, qa.z, qa.w};
      float kv[8] = {ka.x, ka.y, ka.z, ka.w, kb.x, kb.y, kb.z, kb.w};
      #pragma unroll
      for (int i = 0; i < 4; i++)
        #pragma unroll
        for (int j = 0; j < 8; j++)
          acc[i][j] += qv[i] * kv[j];
    }
    #pragma unroll
    for (int i = 0; i < 4; i++){
      float4 w0 = make_float4(fmaxf(acc[i][0]*T,0.f), fmaxf(acc[i][1]*T,0.f),
                              fmaxf(acc[i][2]*T,0.f), fmaxf(acc[i][3]*T,0.f));
      float4 w1 = make_float4(fmaxf(acc[i][4]*T,0.f), fmaxf(acc[i][5]*T,0.f),
                              fmaxf(acc[i][6]*T,0.f), fmaxf(acc[i][7]*T,0.f));
      *(float4*)&at[c0 + i][d0]     = w0;
      *(float4*)&at[c0 + i][d0 + 4] = w1;
    }
    __syncthreads();
    for (int c = 0; c < 64; c++){
      float vv = vs[pp][half * 64 + c];
      float4 aa = *(const float4*)&at[c][d0];
      float4 ab = *(const float4*)&at[c][d0 + 4];
      o[0] += vv * aa.x; o[1] += vv * aa.y; o[2] += vv * aa.z; o[3] += vv * aa.w;
      o[4] += vv * ab.x; o[5] += vv * ab.y; o[6] += vv * ab.z; o[7] += vv * ab.w;
    }
  }
  int h = (hb * 4 + (pp >> 2) + 2) & (cH - 1);
  int w = (wb * 4 + (pp & 3) + 2) & (cW - 1);
  bf16* op = out + (size_t)b * cC * cP + h * cW + w;
  #pragma unroll
  for (int j = 0; j < 8; j++)
    op[(size_t)(d0 + j) * cP] = __float2bfloat16(o[j]);
}

// ---------------- GSA Gram: partial S[c,d], row sumsq, atomic accumulate --------
__global__ void __launch_bounds__(256) k_gram(const bf16* __restrict__ qkv,
                                              float* __restrict__ S,
                                              float* __restrict__ Qn,
                                              float* __restrict__ Kn){
  __shared__ float qs[32][132];
  __shared__ float ks[32][132];
  int blk = blockIdx.x;
  int chunk = blk & 127;
  int bh = blk >> 7;          // b*4+hd, 0..7
  int b = bh >> 2, hd = bh & 3;
  int n0 = chunk * 128;
  int t = threadIdx.x;
  const bf16* base = qkv + (size_t)b * cC3 * cP + n0;
  {
    int r  = t >> 3;
    int c0 = (t & 7) * 16;
    const bf16* qg = base + (size_t)(hd * 32 + r) * cP + c0;
    const bf16* kg = base + (size_t)(128 + hd * 32 + r) * cP + c0;
    #pragma unroll
    for (int i = 0; i < 16; i += 4){
      ushort4 qv = *(const ushort4*)((const unsigned short*)qg + i);
      ushort4 kv = *(const ushort4*)((const unsigned short*)kg + i);
      qs[r][c0 + i]     = bfu2f(qv.x); qs[r][c0 + i + 1] = bfu2f(qv.y);
      qs[r][c0 + i + 2] = bfu2f(qv.z); qs[r][c0 + i + 3] = bfu2f(qv.w);
      ks[r][c0 + i]     = bfu2f(kv.x); ks[r][c0 + i + 1] = bfu2f(kv.y);
      ks[r][c0 + i + 2] = bfu2f(kv.z); ks[r][c0 + i + 3] = bfu2f(kv.w);
    }
  }
  __syncthreads();
  if (t < 64){
    const float* row = (t < 32) ? qs[t] : ks[t - 32];
    float s = 0.f;
    #pragma unroll
    for (int i = 0; i < 128; i += 4){
      float4 v = *(const float4*)(row + i);
      s += v.x*v.x + v.y*v.y + v.z*v.z + v.w*v.w;
    }
    if (t < 32) atomicAdd(&Qn[bh * 32 + t], s);
    else        atomicAdd(&Kn[bh * 32 + (t - 32)], s);
  }
  int cc = (t >> 4) * 2;
  int dd = t & 15;            // covers rows dd and dd+16
  float a00 = 0.f, a01 = 0.f, a10 = 0.f, a11 = 0.f;
  for (int n = 0; n < 128; n += 4){
    float4 q0 = *(const float4*)&qs[cc][n];
    float4 q1 = *(const float4*)&qs[cc + 1][n];
    float4 k0 = *(const float4*)&ks[dd][n];
    float4 k1 = *(const float4*)&ks[dd + 16][n];
    a00 += q0.x*k0.x + q0.y*k0.y + q0.z*k0.z + q0.w*k0.w;
    a01 += q0.x*k1.x + q0.y*k1.y + q0.z*k1.z + q0.w*k1.w;
    a10 += q1.x*k0.x + q1.y*k0.y + q1.z*k0.z + q1.w*k0.w;
    a11 += q1.x*k1.x + q1.y*k1.y + q1.z*k1.z + q1.w*k1.w;
  }
  float* Sb = S + (size_t)bh * 1024;
  atomicAdd(&Sb[cc * 32 + dd], a00);
  atomicAdd(&Sb[cc * 32 + dd + 16], a01);
  atomicAdd(&Sb[(cc + 1) * 32 + dd], a10);
  atomicAdd(&Sb[(cc + 1) * 32 + dd + 16], a11);
}

// ---------------- GSA attn finalize: relu(temp * S / (|q||k|)) ------------------
__global__ void k_fin(const float* __restrict__ S, const float* __restrict__ Qn,
                      const float* __restrict__ Kn, const float* __restrict__ temp,
                      float* __restrict__ A){
  int i = blockIdx.x * 256 + threadIdx.x;
  if (i >= 8 * 1024) return;
  int d = i & 31, c = (i >> 5) & 31, bh = i >> 10;
  float nq = fmaxf(sqrtf(Qn[bh * 32 + c]), 1e-12f);
  float nk = fmaxf(sqrtf(Kn[bh * 32 + d]), 1e-12f);
  float v = S[i] / (nq * nk) * temp[0];
  A[i] = fmaxf(v, 0.f);
}

// ---------------- GSA apply: out[c,n] = sum_d attn[c,d] * v[d,n] ----------------
__global__ void __launch_bounds__(256) k_apply(const bf16* __restrict__ qkv,
                                               const float* __restrict__ A,
                                               bf16* __restrict__ out){
  __shared__ float at[1024];
  int blk = blockIdx.x;
  int tile = blk & 63;
  int bh = blk >> 6;
  int b = bh >> 2, hd = bh & 3;
  int t = threadIdx.x;
  for (int i = t; i < 1024; i += 256) at[i] = A[bh * 1024 + i];
  __syncthreads();
  int n = tile * 256 + t;
  const bf16* vb = qkv + (size_t)b * cC3 * cP + (size_t)(256 + hd * 32) * cP + n;
  float vr[32];
  #pragma unroll
  for (int d = 0; d < 32; d++) vr[d] = b2f(vb[(size_t)d * cP]);
  bf16* ob = out + (size_t)b * cC * cP + (size_t)(hd * 32) * cP + n;
  for (int c = 0; c < 32; c++){
    const float* ar = &at[c * 32];
    float acc = 0.f;
    #pragma unroll
    for (int d = 0; d < 32; d += 4){
      float4 a4 = *(const float4*)(ar + d);
      acc += a4.x * vr[d] + a4.y * vr[d+1] + a4.z * vr[d+2] + a4.w * vr[d+3];
    }
    ob[(size_t)c * cP] = __float2bfloat16(acc);
  }
}

extern "C" void kernel_launch(void* const* d_in, const int* in_sizes, int n_in,
                              void* d_out, int out_size, void* d_ws, size_t ws_size,
                              hipStream_t stream){
  const float* x     = (const float*)d_in[0];
  const float* w_s0  = (const float*)d_in[1];
  const float* b_s0  = (const float*)d_in[2];
  const float* w_s2  = (const float*)d_in[3];
  const float* b_s2  = (const float*)d_in[4];
  const float* rsa_qkv  = (const float*)d_in[5];
  const float* rsa_dw   = (const float*)d_in[6];
  const float* rsa_proj = (const float*)d_in[7];
  const float* rsa_temp = (const float*)d_in[8];
  const float* ffs_in   = (const float*)d_in[9];
  const float* ffs_dw   = (const float*)d_in[10];
  const float* ffs_out  = (const float*)d_in[11];
  const float* w_c0  = (const float*)d_in[12];
  const float* b_c0  = (const float*)d_in[13];
  const float* w_c2  = (const float*)d_in[14];
  const float* b_c2  = (const float*)d_in[15];
  const float* gsa_qkv  = (const float*)d_in[16];
  const float* gsa_dw   = (const float*)d_in[17];
  const float* gsa_proj = (const float*)d_in[18];
  const float* gsa_temp = (const float*)d_in[19];
  const float* ffc_in   = (const float*)d_in[20];
  const float* ffc_dw   = (const float*)d_in[21];
  const float* ffc_out  = (const float*)d_in[22];

  const size_t szC  = (size_t)cB * cC * cP;     // 4194304
  const size_t szC3 = (size_t)cB * cC3 * cP;    // 12582912
  // fp32 trunk buffers
  float* XF = (float*)d_ws;              // x2 (fp32)
  float* XS = XF + szC;                  // x_ (fp32)
  // bf16 activation buffers
  bf16* LO   = (bf16*)(XS + szC);        // LN out / attention out
  bf16* Abuf = LO + szC;                 // conv1x1 qkv / ffn hidden pre-dw
  bf16* Bbuf = Abuf + szC3;              // dwconv output
  // small fp32 tables
  float* S  = (float*)(Bbuf + szC3);     // gsa gram [8][32][32]
  float* Qn = S + 8192;
  float* Kn = Qn + 256;
  float* AT = Kn + 256;                  // gsa attn [8][32][32]
  // total ws ~ 90.5 MB

  dim3 t256(256);

  // ---------------- spatial (RSA) block ----------------
  k_ln<0><<<dim3(cB * cP / 256), t256, 0, stream>>>(x, x, w_s0, b_s0, LO, 126, 126);
  k_gemm<0><<<dim3(cP/64, 6, cB), t256, 0, stream>>>(rsa_qkv, LO, nullptr, Abuf, cC3, cC);
  k_dw<0><<<dim3(cB * cC3 * cP / 256), t256, 0, stream>>>(Abuf, rsa_dw, Bbuf, cC3);
  k_rsa<<<dim3(cB * cNW), t256, 0, stream>>>(Bbuf, rsa_temp, LO);   // writes unrolled frame
  k_gemm<1><<<dim3(cP/64, 2, cB), t256, 0, stream>>>(rsa_proj, LO, nullptr, XS, cC, cC);
  k_ln<1><<<dim3(cB * cP / 256), t256, 0, stream>>>(x, XS, w_s2, b_s2, LO, 0, 0);
  k_gemm<0><<<dim3(cP/64, 6, cB), t256, 0, stream>>>(ffs_in, LO, nullptr, Abuf, cHID, cC);
  k_dw<1><<<dim3(cB * cHID * cP / 256), t256, 0, stream>>>(Abuf, ffs_dw, Bbuf, cHID);
  k_gemm<2><<<dim3(cP/64, 2, cB), t256, 0, stream>>>(ffs_out, Bbuf, XS, XF, cC, cHID);
  // XF now holds x2 (fp32)

  // ---------------- channel (GSA) block ----------------
  k_ln<0><<<dim3(cB * cP / 256), t256, 0, stream>>>(XF, XF, w_c0, b_c0, LO, 0, 0);
  k_gemm<0><<<dim3(cP/64, 6, cB), t256, 0, stream>>>(gsa_qkv, LO, nullptr, Abuf, cC3, cC);
  k_dw<0><<<dim3(cB * cC3 * cP / 256), t256, 0, stream>>>(Abuf, gsa_dw, Bbuf, cC3);
  k_zero<<<dim3((8704 + 255) / 256), t256, 0, stream>>>(S, 8704);
  k_gram<<<dim3(1024), t256, 0, stream>>>(Bbuf, S, Qn, Kn);
  k_fin<<<dim3(32), t256, 0, stream>>>(S, Qn, Kn, gsa_temp, AT);
  k_apply<<<dim3(512), t256, 0, stream>>>(Bbuf, AT, LO);
  k_gemm<1><<<dim3(cP/64, 2, cB), t256, 0, stream>>>(gsa_proj, LO, nullptr, XS, cC, cC);
  k_ln<1><<<dim3(cB * cP / 256), t256, 0, stream>>>(XF, XS, w_c2, b_c2, LO, 0, 0);
  k_gemm<0><<<dim3(cP/64, 6, cB), t256, 0, stream>>>(ffc_in, LO, nullptr, Abuf, cHID, cC);
  k_dw<1><<<dim3(cB * cHID * cP / 256), t256, 0, stream>>>(Abuf, ffc_dw, Bbuf, cHID);
  k_gemm<2><<<dim3(cP/64, 2, cB), t256, 0, stream>>>(ffc_out, Bbuf, XS, d_out, cC, cHID);
}